// Round 4
// baseline (582.562 us; speedup 1.0000x reference)
//
#include <hip/hip_runtime.h>
#include <stdint.h>

#define GAS __attribute__((address_space(1)))
#define LAS __attribute__((address_space(3)))

typedef short bf16x8 __attribute__((ext_vector_type(8)));
typedef float f32x4 __attribute__((ext_vector_type(4)));
typedef unsigned short u16x8 __attribute__((ext_vector_type(8)));

__device__ __forceinline__ unsigned short f2bf(float f) {
  union { float f; uint32_t u; } v; v.f = f;
  uint32_t r = v.u + 0x7FFFu + ((v.u >> 16) & 1u);
  return (unsigned short)(r >> 16);
}

__device__ __forceinline__ uint32_t cvtpk(float lo, float hi) {
  uint32_t r;
  asm("v_cvt_pk_bf16_f32 %0, %1, %2" : "=v"(r) : "v"(lo), "v"(hi));
  return r;
}

// ------------- merged transpose + cast: w1 and w2 in one launch -------------
// y < 392: w1 [12544,1024] -> W1T [1024,12544]; else w2 [1024,1024] -> W2T [1024,1024]
__global__ __launch_bounds__(256) void prep_transpose(const float* __restrict__ w1,
                                                      const float* __restrict__ w2,
                                                      unsigned short* __restrict__ W1T,
                                                      unsigned short* __restrict__ W2T) {
  __shared__ unsigned short tile[32][33];
  int tx = threadIdx.x, ty = threadIdx.y;  // 32 x 8
  const float* src;
  unsigned short* dst;
  int R, yb;
  if ((int)blockIdx.y < 392) {
    src = w1; dst = W1T; R = 12544; yb = blockIdx.y;
  } else {
    src = w2; dst = W2T; R = 1024; yb = blockIdx.y - 392;
  }
  const int C = 1024;
  int r0 = yb * 32, c0 = blockIdx.x * 32;
#pragma unroll
  for (int i = 0; i < 32; i += 8)
    tile[ty + i][tx] = f2bf(src[(long)(r0 + ty + i) * C + c0 + tx]);
  __syncthreads();
#pragma unroll
  for (int i = 0; i < 32; i += 8)
    dst[(long)(c0 + ty + i) * R + r0 + tx] = tile[tx][ty + i];
}

// ---------- GEMM1 fused: fp32 A read + cvt in-kernel, no split-K, fused bias+relu+cvt ----------
// A: [M,K] fp32 (features), Bt: [1024,K] bf16 (w1^T). Tile 128M x 64N, BK=64.
// Grid 512 = 32(by) x 16(bx), XCD map: 16 bx sharing one A-panel on one XCD (A L2-reuse).
// A staged via regs (8 dwordx4 f32 -> cvt_pk -> 4 ds_write_b128, XOR-swizzled k-chunks),
// prefetched one K-tile ahead (full-iteration latency cover). B via global_load_lds,
// one tile ahead. One barrier per K-tile. Direct bf16 store with bias+relu.
__global__ __launch_bounds__(256, 2) void gemm1_fused(const float* __restrict__ A,
                                                      const unsigned short* __restrict__ Bt,
                                                      const float* __restrict__ bias,
                                                      unsigned short* __restrict__ H1,
                                                      int M, int K, int kIters) {
  __shared__ unsigned short lA[2 * 8192];  // 2 x 128x64 bf16 = 2 x 16 KB
  __shared__ unsigned short lB[2 * 4096];  // 2 x  64x64 bf16 = 2 x  8 KB
  const int tid = threadIdx.x;
  const int lane = tid & 63;
  const int wave = tid >> 6;
  const int wm = wave >> 1, wn = wave & 1;  // wave tile 64m x 32n

  const int b = blockIdx.x;
  const int xcd = b & 7;
  const int slot = b >> 3;               // 0..63
  const int bx = slot & 15;              // N-block 0..15, fastest within XCD
  const int by = xcd * 4 + (slot >> 4);  // M-block 0..31

  const int rowBase = by * 128;
  const int colBase = bx * 64;

  f32x4 acc[4][2];
#pragma unroll
  for (int i = 0; i < 4; i++)
#pragma unroll
    for (int j = 0; j < 2; j++) acc[i][j] = (f32x4){0.f, 0.f, 0.f, 0.f};

  // A slots: 1024 = 128 rows x 8 q-chunks; 4 per thread. Slot (r,q) holds global
  // k-chunk q^(r&7) (XOR swizzle). Indices fit int32 (max ~50.2M elems).
  int gA[4], aLds[4];
#pragma unroll
  for (int i = 0; i < 4; ++i) {
    int s = i * 256 + tid;
    int r = s >> 3;
    int q = s & 7;
    int kq = (q ^ (r & 7)) * 8;
    int ar = rowBase + r;
    if (ar >= M) ar = M - 1;  // clamp; store masked later
    gA[i] = ar * K + kq;
    aLds[i] = s * 8;
  }
  // B slots: 512 = 64 rows x 8 q; 2 per thread.
  int gB[2], bLds[2];
#pragma unroll
  for (int i = 0; i < 2; ++i) {
    int s = i * 256 + tid;
    int r = s >> 3;
    int q = s & 7;
    int kq = (q ^ (r & 7)) * 8;
    gB[i] = (colBase + r) * K + kq;
    bLds[i] = s * 8;
  }

  float4 pre[4][2];  // A prefetch regs (one K-tile ahead)

  // ---- prologue: tile 0 ----
#pragma unroll
  for (int i = 0; i < 2; ++i)
    __builtin_amdgcn_global_load_lds((const GAS void*)(Bt + gB[i]),
                                     (LAS void*)(lB + bLds[i]), 16, 0, 0);
#pragma unroll
  for (int i = 0; i < 4; ++i) {
    const float4* p = (const float4*)(A + gA[i]);
    pre[i][0] = p[0];
    pre[i][1] = p[1];
  }
#pragma unroll
  for (int i = 0; i < 4; ++i) {
    uint4 v;
    v.x = cvtpk(pre[i][0].x, pre[i][0].y);
    v.y = cvtpk(pre[i][0].z, pre[i][0].w);
    v.z = cvtpk(pre[i][1].x, pre[i][1].y);
    v.w = cvtpk(pre[i][1].z, pre[i][1].w);
    *(uint4*)(lA + aLds[i]) = v;
  }
  asm volatile("s_waitcnt vmcnt(0)" ::: "memory");   // B(t0) landed
  asm volatile("s_waitcnt lgkmcnt(0)" ::: "memory"); // A ds_writes done
  __builtin_amdgcn_s_barrier();
  asm volatile("" ::: "memory");
  // issue A regs for tile 1 (in flight during tile-0 compute)
#pragma unroll
  for (int i = 0; i < 4; ++i) {
    const float4* p = (const float4*)(A + gA[i] + 64);
    pre[i][0] = p[0];
    pre[i][1] = p[1];
  }

  const int l15 = lane & 15;
  const int lxor = lane & 7;
  const int chi = lane >> 4;

  for (int t = 0; t < kIters; ++t) {
    const int cur = t & 1;
    const int nxt = cur ^ 1;
    const int cA = cur * 8192, nA = nxt * 8192;
    const int cB = cur * 4096, nB = nxt * 4096;
    const bool more = (t + 1 < kIters);

    // issue B(t+1) -> lB[nxt] (covered by this tile's compute)
    if (more) {
      const int kc = (t + 1) * 64;
#pragma unroll
      for (int i = 0; i < 2; ++i)
        __builtin_amdgcn_global_load_lds((const GAS void*)(Bt + gB[i] + kc),
                                         (LAS void*)(lB + nB + bLds[i]), 16, 0, 0);
    }

    // compute tile t
    bf16x8 af[4][2], bf[2][2];
#pragma unroll
    for (int ks = 0; ks < 2; ++ks) {
      const int slotk = (((ks * 4) + chi) ^ lxor) << 3;
#pragma unroll
      for (int i = 0; i < 4; ++i) {
        const int mr = wm * 64 + i * 16 + l15;
        af[i][ks] = *(const bf16x8*)(lA + cA + mr * 64 + slotk);
      }
#pragma unroll
      for (int j = 0; j < 2; ++j) {
        const int nr = wn * 32 + j * 16 + l15;
        bf[j][ks] = *(const bf16x8*)(lB + cB + nr * 64 + slotk);
      }
    }
    __builtin_amdgcn_s_setprio(1);
#pragma unroll
    for (int i = 0; i < 4; ++i)
#pragma unroll
      for (int j = 0; j < 2; ++j) {
        acc[i][j] = __builtin_amdgcn_mfma_f32_16x16x32_bf16(af[i][0], bf[j][0], acc[i][j], 0, 0, 0);
        acc[i][j] = __builtin_amdgcn_mfma_f32_16x16x32_bf16(af[i][1], bf[j][1], acc[i][j], 0, 0, 0);
      }
    __builtin_amdgcn_s_setprio(0);

    if (more) {
      // pre(t+1) has had a full iteration in flight; B(t+1) covered by compute above
      asm volatile("s_waitcnt vmcnt(0)" ::: "memory");
#pragma unroll
      for (int i = 0; i < 4; ++i) {
        uint4 v;
        v.x = cvtpk(pre[i][0].x, pre[i][0].y);
        v.y = cvtpk(pre[i][0].z, pre[i][0].w);
        v.z = cvtpk(pre[i][1].x, pre[i][1].y);
        v.w = cvtpk(pre[i][1].z, pre[i][1].w);
        *(uint4*)(lA + nA + aLds[i]) = v;
      }
      if (t + 2 < kIters) {
        const int kc2 = (t + 2) * 64;
#pragma unroll
        for (int i = 0; i < 4; ++i) {
          const float4* p = (const float4*)(A + gA[i] + kc2);
          pre[i][0] = p[0];
          pre[i][1] = p[1];
        }
      }
      asm volatile("s_waitcnt lgkmcnt(0)" ::: "memory");  // ds_writes visible
    }
    __builtin_amdgcn_s_barrier();
    asm volatile("" ::: "memory");
  }

  // epilogue: bias + relu + bf16, direct store. C/D: col=lane&15, row=(lane>>4)*4+reg
  const int cq = lane & 15;
  const int rq = (lane >> 4) << 2;
#pragma unroll
  for (int i = 0; i < 4; ++i) {
#pragma unroll
    for (int j = 0; j < 2; ++j) {
      const int col = colBase + wn * 32 + j * 16 + cq;
      const float bv = bias[col];
#pragma unroll
      for (int r = 0; r < 4; ++r) {
        int grow = rowBase + wm * 64 + i * 16 + rq + r;
        if (grow < M) {
          float v = acc[i][j][r] + bv;
          H1[(long)grow * 1024 + col] = f2bf(v > 0.f ? v : 0.f);
        }
      }
    }
  }
}

// ---------- GEMM2: 128x64 tile, no split-K, direct store, bias+relu ----------
__global__ __launch_bounds__(256, 2) void gemm2_direct(const unsigned short* __restrict__ A,
                                                       const unsigned short* __restrict__ Bt,
                                                       const float* __restrict__ bias,
                                                       float* __restrict__ Cv, int M) {
  const int K = 1024;
  __shared__ unsigned short lA[128 * 64];  // 16 KB
  __shared__ unsigned short lB[64 * 64];   // 8 KB
  const int tid = threadIdx.x;
  const int lane = tid & 63;
  const int wave = tid >> 6;
  const int wm = wave >> 1, wn = wave & 1;  // wave tile 64m x 32n

  const int b = blockIdx.x;
  const int xcd = b & 7;
  const int slot = b >> 3;               // 0..63
  const int bx = slot & 15;              // N-block 0..15
  const int by = xcd * 4 + (slot >> 4);  // M-block 0..31

  const long rowBase = (long)by * 128;
  const long colBase = (long)bx * 64;

  f32x4 acc[4][2];
#pragma unroll
  for (int i = 0; i < 4; i++)
#pragma unroll
    for (int j = 0; j < 2; j++) acc[i][j] = (f32x4){0.f, 0.f, 0.f, 0.f};

  long gA[4], gB[2];
#pragma unroll
  for (int it = 0; it < 4; ++it) {
    int f = it * 256 + tid;
    int r = f >> 3;
    int q = f & 7;
    int kq = (q ^ (r & 7)) * 8;
    long ar = rowBase + r;
    if (ar >= M) ar = M - 1;
    gA[it] = ar * (long)K + kq;
  }
#pragma unroll
  for (int it = 0; it < 2; ++it) {
    int f = it * 256 + tid;
    int r = f >> 3;
    int q = f & 7;
    int kq = (q ^ (r & 7)) * 8;
    gB[it] = ((long)(colBase + r)) * K + kq;
  }

  for (int ki = 0; ki < 16; ++ki) {
    const long kc = (long)ki * 64;
#pragma unroll
    for (int it = 0; it < 4; ++it) {
      int f = it * 256 + tid;
      __builtin_amdgcn_global_load_lds((const GAS void*)(A + gA[it] + kc),
                                       (LAS void*)(lA + f * 8), 16, 0, 0);
    }
#pragma unroll
    for (int it = 0; it < 2; ++it) {
      int f = it * 256 + tid;
      __builtin_amdgcn_global_load_lds((const GAS void*)(Bt + gB[it] + kc),
                                       (LAS void*)(lB + f * 8), 16, 0, 0);
    }
    __syncthreads();
#pragma unroll
    for (int ks = 0; ks < 64; ks += 32) {
      bf16x8 af[4], bf[2];
      const int c = (ks >> 3) + (lane >> 4);
      const int slotk = (c ^ (lane & 7)) << 3;
      const int mr = wm * 64 + (lane & 15);
      const int nr = wn * 32 + (lane & 15);
#pragma unroll
      for (int i = 0; i < 4; i++)
        af[i] = *(const bf16x8*)(lA + (mr + i * 16) * 64 + slotk);
#pragma unroll
      for (int j = 0; j < 2; j++)
        bf[j] = *(const bf16x8*)(lB + (nr + j * 16) * 64 + slotk);
#pragma unroll
      for (int i = 0; i < 4; i++)
#pragma unroll
        for (int j = 0; j < 2; j++)
          acc[i][j] = __builtin_amdgcn_mfma_f32_16x16x32_bf16(af[i], bf[j], acc[i][j], 0, 0, 0);
    }
    __syncthreads();
  }

  const int cq = lane & 15;
  const int rq = (lane >> 4) * 4;
#pragma unroll
  for (int i = 0; i < 4; i++) {
#pragma unroll
    for (int j = 0; j < 2; j++) {
      int col = (int)colBase + wn * 32 + j * 16 + cq;
      float bv = bias[col];
#pragma unroll
      for (int r = 0; r < 4; r++) {
        long grow = rowBase + wm * 64 + i * 16 + rq + r;
        if (grow < M) {
          float v = acc[i][j][r] + bv;
          Cv[grow * 1024 + col] = v > 0.f ? v : 0.f;
        }
      }
    }
  }
}

// ---------------- heads ----------------
__global__ __launch_bounds__(256) void head_kernel(
    const float* __restrict__ H2, const float* __restrict__ wc, const float* __restrict__ bc,
    const float* __restrict__ wr, const float* __restrict__ br, const float* __restrict__ boxes,
    float* __restrict__ cls, float* __restrict__ bout, float* __restrict__ rois) {
  const int lane = threadIdx.x & 63;
  const int wave = threadIdx.x >> 6;
  const int row = blockIdx.x * 4 + wave;  // 1000 * 4 = 4000 rows
  const float* h = H2 + (long)row * 1024;
  float acc[16];
#pragma unroll
  for (int c = 0; c < 16; c++) acc[c] = 0.f;
#pragma unroll
  for (int i = 0; i < 16; i++) {
    int d = i * 64 + lane;
    float hv = h[d];
#pragma unroll
    for (int c = 0; c < 11; c++) acc[c] += hv * wc[d * 11 + c];
#pragma unroll
    for (int c = 0; c < 5; c++) acc[11 + c] += hv * wr[d * 5 + c];
  }
#pragma unroll
  for (int off = 32; off >= 1; off >>= 1) {
#pragma unroll
    for (int c = 0; c < 16; c++) acc[c] += __shfl_down(acc[c], off);
  }
  if (lane == 0) {
#pragma unroll
    for (int c = 0; c < 11; c++) cls[row * 11 + c] = acc[c] + bc[c];
#pragma unroll
    for (int c = 0; c < 5; c++) {
      float rg = acc[11 + c] + br[c];
      float bx = boxes[row * 5 + c];
      bout[row * 5 + c] = bx + rg;
      rois[row * 5 + c] = bx;
    }
  }
}

extern "C" void kernel_launch(void* const* d_in, const int* in_sizes, int n_in,
                              void* d_out, int out_size, void* d_ws, size_t ws_size,
                              hipStream_t stream) {
  const float* features = (const float*)d_in[0];  // [4000,12544] fp32
  const float* boxes = (const float*)d_in[1];
  const float* w1 = (const float*)d_in[2];  // [12544,1024]
  const float* b1 = (const float*)d_in[3];
  const float* w2 = (const float*)d_in[4];  // [1024,1024]
  const float* b2 = (const float*)d_in[5];
  const float* wc = (const float*)d_in[6];  // [1024,11]
  const float* bc = (const float*)d_in[7];
  const float* wr = (const float*)d_in[8];  // [1024,5]
  const float* br = (const float*)d_in[9];

  char* ws = (char*)d_ws;
  unsigned short* W1T = (unsigned short*)ws;               // 25,690,112 B
  unsigned short* W2T = (unsigned short*)(ws + 25690112);  //  2,097,152 B
  unsigned short* H1  = (unsigned short*)(ws + 27787264);  //  8,192,000 B
  float*          H2  = (float*)(ws + 35979264);           // 16,384,000 B
  // total ws used: 52,363,264 B

  // 1) w1 -> W1T bf16 [1024,12544]; w2 -> W2T bf16 [1024,1024] (merged)
  prep_transpose<<<dim3(32, 424), dim3(32, 8), 0, stream>>>(w1, w2, W1T, W2T);
  // 2) GEMM1 fused: H1 = bf16(relu(features @ w1 + b1)), fp32 A read + in-kernel cvt
  gemm1_fused<<<512, 256, 0, stream>>>(features, W1T, b1, H1, 4000, 12544, 196);
  // 3) GEMM2 direct: H2 = relu(H1 @ w2 + b2)
  gemm2_direct<<<512, 256, 0, stream>>>(H1, W2T, b2, H2, 4000);
  // 4) heads
  float* cls = (float*)d_out;   // [4000,11]
  float* bout = cls + 44000;    // [4000,5]
  float* rois = cls + 64000;    // [4000,5]
  head_kernel<<<1000, 256, 0, stream>>>(H2, wc, bc, wr, br, boxes, cls, bout, rois);
}

// Round 5
// 550.378 us; speedup vs baseline: 1.0585x; 1.0585x over previous
//
#include <hip/hip_runtime.h>
#include <stdint.h>

#define GAS __attribute__((address_space(1)))
#define LAS __attribute__((address_space(3)))

typedef short bf16x8 __attribute__((ext_vector_type(8)));
typedef float f32x4 __attribute__((ext_vector_type(4)));
typedef unsigned short u16x8 __attribute__((ext_vector_type(8)));

__device__ __forceinline__ unsigned short f2bf(float f) {
  union { float f; uint32_t u; } v; v.f = f;
  uint32_t r = v.u + 0x7FFFu + ((v.u >> 16) & 1u);
  return (unsigned short)(r >> 16);
}

// ------------- merged transpose + cast: w1 and w2 in one launch -------------
// y < 392: w1 [12544,1024] -> W1T [1024,12544]; else w2 [1024,1024] -> W2T [1024,1024]
__global__ __launch_bounds__(256) void prep_transpose(const float* __restrict__ w1,
                                                      const float* __restrict__ w2,
                                                      unsigned short* __restrict__ W1T,
                                                      unsigned short* __restrict__ W2T) {
  __shared__ unsigned short tile[32][33];
  int tx = threadIdx.x, ty = threadIdx.y;  // 32 x 8
  const float* src;
  unsigned short* dst;
  int R, yb;
  if ((int)blockIdx.y < 392) {
    src = w1; dst = W1T; R = 12544; yb = blockIdx.y;
  } else {
    src = w2; dst = W2T; R = 1024; yb = blockIdx.y - 392;
  }
  const int C = 1024;
  int r0 = yb * 32, c0 = blockIdx.x * 32;
#pragma unroll
  for (int i = 0; i < 32; i += 8)
    tile[ty + i][tx] = f2bf(src[(long)(r0 + ty + i) * C + c0 + tx]);
  __syncthreads();
#pragma unroll
  for (int i = 0; i < 32; i += 8)
    dst[(long)(c0 + ty + i) * R + r0 + tx] = tile[tx][ty + i];
}

// ---------- GEMM1: r1 schedule (128x128, split-K x4, 2-barrier, 4 blk/CU TLP), ----------
// ---------- but A read as fp32 directly (reg-stage + f2bf + ds_write_b128)   ----------
// A: [M,K] fp32 (features), Bt: [1024,K] bf16. Logical grid 8(xN) x 32(yM) x 4(zK)
// flattened to 1024 with XCD remap: the 8 N-blocks sharing one A-slice land on ONE XCD.
// LDS stays 32 KB -> 4 blocks/CU co-resident (the proven TLP latency-hiding).
__global__ __launch_bounds__(256, 2) void gemm1_f32a(const float* __restrict__ A,
                                                     const unsigned short* __restrict__ Bt,
                                                     float* __restrict__ Cv, int M, int K,
                                                     int kIters) {
  __shared__ unsigned short lA[128 * 64];  // 16 KB
  __shared__ unsigned short lB[128 * 64];  // 16 KB
  const int tid = threadIdx.x;
  const int lane = tid & 63;
  const int wave = tid >> 6;
  const int wm = wave >> 1, wn = wave & 1;

  const int b = blockIdx.x;
  const int xcd = b & 7;
  const int slot = b >> 3;
  const int bx = slot & 7;                // N-block, fastest within XCD
  const int pg = xcd * 16 + (slot >> 3);  // (y,z) 0..127
  const int by = pg & 31;
  const int bz = pg >> 5;

  const long rowBase = (long)by * 128;
  const long colBase = (long)bx * 128;
  const int kStart = bz * kIters * 64;

  f32x4 acc[4][4];
#pragma unroll
  for (int i = 0; i < 4; i++)
#pragma unroll
    for (int j = 0; j < 4; j++) acc[i][j] = (f32x4){0.f, 0.f, 0.f, 0.f};

  // flat f = it*256+tid -> LDS slot (r=f>>3, q=f&7) at elem f*8.
  // XOR swizzle: slot (r,q) holds GLOBAL chunk q^(r&7) -> conflict-free fragment reads.
  long gA[4], gB[4];
  int aLds[4];
#pragma unroll
  for (int it = 0; it < 4; ++it) {
    int f = it * 256 + tid;
    int r = f >> 3;
    int q = f & 7;
    int kq = ((q ^ (r & 7)) * 8) + kStart;
    long ar = rowBase + r;
    if (ar >= M) ar = M - 1;  // clamp: stays in-bounds, C-write masked later
    gA[it] = ar * (long)K + kq;
    gB[it] = ((long)(colBase + r)) * K + kq;
    aLds[it] = f * 8;
  }

  for (int ki = 0; ki < kIters; ++ki) {
    const long kc = (long)ki * 64;
    // B: async DMA into LDS (issues first, overlaps A's register-load latency)
#pragma unroll
    for (int it = 0; it < 4; ++it) {
      int f = it * 256 + tid;
      __builtin_amdgcn_global_load_lds((const GAS void*)(Bt + gB[it] + kc),
                                       (LAS void*)(lB + f * 8), 16, 0, 0);
    }
    // A: fp32 -> regs -> bf16 -> LDS (same slot layout as the old DMA path)
#pragma unroll
    for (int it = 0; it < 4; ++it) {
      const float4* p = (const float4*)(A + gA[it] + kc);
      float4 a = p[0], c = p[1];
      u16x8 v;
      v[0] = f2bf(a.x); v[1] = f2bf(a.y); v[2] = f2bf(a.z); v[3] = f2bf(a.w);
      v[4] = f2bf(c.x); v[5] = f2bf(c.y); v[6] = f2bf(c.z); v[7] = f2bf(c.w);
      *(u16x8*)(lA + aLds[it]) = v;
    }
    __syncthreads();
#pragma unroll
    for (int ks = 0; ks < 64; ks += 32) {
      bf16x8 af[4], bf[4];
      const int c = (ks >> 3) + (lane >> 4);
      const int slotk = (c ^ (lane & 7)) << 3;
      const int mr = wm * 64 + (lane & 15);
      const int nr = wn * 64 + (lane & 15);
#pragma unroll
      for (int i = 0; i < 4; i++)
        af[i] = *(const bf16x8*)(lA + (mr + i * 16) * 64 + slotk);
#pragma unroll
      for (int i = 0; i < 4; i++)
        bf[i] = *(const bf16x8*)(lB + (nr + i * 16) * 64 + slotk);
#pragma unroll
      for (int i = 0; i < 4; i++)
#pragma unroll
        for (int j = 0; j < 4; j++)
          acc[i][j] = __builtin_amdgcn_mfma_f32_16x16x32_bf16(af[i], bf[j], acc[i][j], 0, 0, 0);
    }
    __syncthreads();
  }

  // C/D layout: col=lane&15, row=(lane>>4)*4+reg  [m89-verified]
  const int cq = lane & 15;
  const int rq = (lane >> 4) * 4;
#pragma unroll
  for (int i = 0; i < 4; i++) {
#pragma unroll
    for (int j = 0; j < 4; j++) {
      int col = (int)colBase + wn * 64 + j * 16 + cq;
#pragma unroll
      for (int r = 0; r < 4; r++) {
        long grow = rowBase + wm * 64 + i * 16 + rq + r;
        if (grow < M) unsafeAtomicAdd(&Cv[grow * 1024 + col], acc[i][j][r]);
      }
    }
  }
}

// ---------- GEMM2 fused: A = relu(H1f + b1) computed in-staging (fp32 in, bf16 LDS) ----------
// H1f: [M,1024] fp32 pre-bias accumulator. Bt: [1024,1024] bf16 (w2^T).
// Tile 128x64, grid 512 = 16(xN) x 32(yM), 2 blk/CU. Epilogue: bias2+relu -> H2 fp32.
__global__ __launch_bounds__(256, 2) void gemm2_fused(const float* __restrict__ H1f,
                                                      const float* __restrict__ bias1,
                                                      const unsigned short* __restrict__ Bt,
                                                      const float* __restrict__ bias2,
                                                      float* __restrict__ Cv, int M) {
  const int K = 1024;
  __shared__ unsigned short lA[128 * 64];  // 16 KB
  __shared__ unsigned short lB[64 * 64];   // 8 KB
  const int tid = threadIdx.x;
  const int lane = tid & 63;
  const int wave = tid >> 6;
  const int wm = wave >> 1, wn = wave & 1;  // wave tile 64m x 32n

  const int b = blockIdx.x;
  const int xcd = b & 7;
  const int slot = b >> 3;               // 0..63
  const int bx = slot & 15;              // N-block 0..15
  const int by = xcd * 4 + (slot >> 4);  // M-block 0..31

  const long rowBase = (long)by * 128;
  const long colBase = (long)bx * 64;

  f32x4 acc[4][2];
#pragma unroll
  for (int i = 0; i < 4; i++)
#pragma unroll
    for (int j = 0; j < 2; j++) acc[i][j] = (f32x4){0.f, 0.f, 0.f, 0.f};

  long gA[4];
  int aLds[4], aKq[4];
#pragma unroll
  for (int it = 0; it < 4; ++it) {
    int f = it * 256 + tid;
    int r = f >> 3;
    int q = f & 7;
    int kq = (q ^ (r & 7)) * 8;
    long ar = rowBase + r;
    if (ar >= M) ar = M - 1;
    gA[it] = ar * (long)K + kq;
    aLds[it] = f * 8;
    aKq[it] = kq;
  }
  long gB[2];
#pragma unroll
  for (int it = 0; it < 2; ++it) {
    int f = it * 256 + tid;
    int r = f >> 3;
    int q = f & 7;
    int kq = (q ^ (r & 7)) * 8;
    gB[it] = ((long)(colBase + r)) * K + kq;
  }

  for (int ki = 0; ki < 16; ++ki) {
    const long kc = (long)ki * 64;
#pragma unroll
    for (int it = 0; it < 2; ++it) {
      int f = it * 256 + tid;
      __builtin_amdgcn_global_load_lds((const GAS void*)(Bt + gB[it] + kc),
                                       (LAS void*)(lB + f * 8), 16, 0, 0);
    }
    // A: fp32 + bias1 + relu -> bf16 -> LDS
#pragma unroll
    for (int it = 0; it < 4; ++it) {
      const float4* p = (const float4*)(H1f + gA[it] + kc);
      const float4* bp = (const float4*)(bias1 + kc + aKq[it]);
      float4 a = p[0], c = p[1];
      float4 ba = bp[0], bb = bp[1];
      u16x8 v;
      v[0] = f2bf(fmaxf(a.x + ba.x, 0.f)); v[1] = f2bf(fmaxf(a.y + ba.y, 0.f));
      v[2] = f2bf(fmaxf(a.z + ba.z, 0.f)); v[3] = f2bf(fmaxf(a.w + ba.w, 0.f));
      v[4] = f2bf(fmaxf(c.x + bb.x, 0.f)); v[5] = f2bf(fmaxf(c.y + bb.y, 0.f));
      v[6] = f2bf(fmaxf(c.z + bb.z, 0.f)); v[7] = f2bf(fmaxf(c.w + bb.w, 0.f));
      *(u16x8*)(lA + aLds[it]) = v;
    }
    __syncthreads();
#pragma unroll
    for (int ks = 0; ks < 64; ks += 32) {
      bf16x8 af[4], bf[2];
      const int c = (ks >> 3) + (lane >> 4);
      const int slotk = (c ^ (lane & 7)) << 3;
      const int mr = wm * 64 + (lane & 15);
      const int nr = wn * 32 + (lane & 15);
#pragma unroll
      for (int i = 0; i < 4; i++)
        af[i] = *(const bf16x8*)(lA + (mr + i * 16) * 64 + slotk);
#pragma unroll
      for (int j = 0; j < 2; j++)
        bf[j] = *(const bf16x8*)(lB + (nr + j * 16) * 64 + slotk);
#pragma unroll
      for (int i = 0; i < 4; i++)
#pragma unroll
        for (int j = 0; j < 2; j++)
          acc[i][j] = __builtin_amdgcn_mfma_f32_16x16x32_bf16(af[i], bf[j], acc[i][j], 0, 0, 0);
    }
    __syncthreads();
  }

  const int cq = lane & 15;
  const int rq = (lane >> 4) * 4;
#pragma unroll
  for (int i = 0; i < 4; i++) {
#pragma unroll
    for (int j = 0; j < 2; j++) {
      int col = (int)colBase + wn * 32 + j * 16 + cq;
      float bv = bias2[col];
#pragma unroll
      for (int r = 0; r < 4; r++) {
        long grow = rowBase + wm * 64 + i * 16 + rq + r;
        if (grow < M) {
          float v = acc[i][j][r] + bv;
          Cv[grow * 1024 + col] = v > 0.f ? v : 0.f;
        }
      }
    }
  }
}

// ---------------- heads ----------------
__global__ __launch_bounds__(256) void head_kernel(
    const float* __restrict__ H2, const float* __restrict__ wc, const float* __restrict__ bc,
    const float* __restrict__ wr, const float* __restrict__ br, const float* __restrict__ boxes,
    float* __restrict__ cls, float* __restrict__ bout, float* __restrict__ rois) {
  const int lane = threadIdx.x & 63;
  const int wave = threadIdx.x >> 6;
  const int row = blockIdx.x * 4 + wave;  // 1000 * 4 = 4000 rows
  const float* h = H2 + (long)row * 1024;
  float acc[16];
#pragma unroll
  for (int c = 0; c < 16; c++) acc[c] = 0.f;
#pragma unroll
  for (int i = 0; i < 16; i++) {
    int d = i * 64 + lane;
    float hv = h[d];
#pragma unroll
    for (int c = 0; c < 11; c++) acc[c] += hv * wc[d * 11 + c];
#pragma unroll
    for (int c = 0; c < 5; c++) acc[11 + c] += hv * wr[d * 5 + c];
  }
#pragma unroll
  for (int off = 32; off >= 1; off >>= 1) {
#pragma unroll
    for (int c = 0; c < 16; c++) acc[c] += __shfl_down(acc[c], off);
  }
  if (lane == 0) {
#pragma unroll
    for (int c = 0; c < 11; c++) cls[row * 11 + c] = acc[c] + bc[c];
#pragma unroll
    for (int c = 0; c < 5; c++) {
      float rg = acc[11 + c] + br[c];
      float bx = boxes[row * 5 + c];
      bout[row * 5 + c] = bx + rg;
      rois[row * 5 + c] = bx;
    }
  }
}

extern "C" void kernel_launch(void* const* d_in, const int* in_sizes, int n_in,
                              void* d_out, int out_size, void* d_ws, size_t ws_size,
                              hipStream_t stream) {
  const float* features = (const float*)d_in[0];  // [4000,12544] fp32
  const float* boxes = (const float*)d_in[1];
  const float* w1 = (const float*)d_in[2];  // [12544,1024]
  const float* b1 = (const float*)d_in[3];
  const float* w2 = (const float*)d_in[4];  // [1024,1024]
  const float* b2 = (const float*)d_in[5];
  const float* wc = (const float*)d_in[6];  // [1024,11]
  const float* bc = (const float*)d_in[7];
  const float* wr = (const float*)d_in[8];  // [1024,5]
  const float* br = (const float*)d_in[9];

  char* ws = (char*)d_ws;
  unsigned short* W1T = (unsigned short*)ws;               // 25,690,112 B
  unsigned short* W2T = (unsigned short*)(ws + 25690112);  //  2,097,152 B
  float*          H1f = (float*)(ws + 27787264);           // 16,384,000 B
  float*          H2  = (float*)(ws + 44171264);           // 16,384,000 B
  // total ws used: 60,555,264 B

  // 0) zero split-K accumulator
  hipMemsetAsync(H1f, 0, 16384000, stream);
  // 1) w1 -> W1T bf16 [1024,12544]; w2 -> W2T bf16 [1024,1024] (merged)
  prep_transpose<<<dim3(32, 424), dim3(32, 8), 0, stream>>>(w1, w2, W1T, W2T);
  // 2) GEMM1: r1 schedule, fp32 A in-kernel cast, split-K x4 atomic -> H1f
  gemm1_f32a<<<1024, 256, 0, stream>>>(features, W1T, H1f, 4000, 12544, 49);
  // 3) GEMM2 fused: H2 = relu( relu(H1f + b1) @ w2 + b2 )
  gemm2_fused<<<512, 256, 0, stream>>>(H1f, b1, W2T, b2, H2, 4000);
  // 4) heads
  float* cls = (float*)d_out;   // [4000,11]
  float* bout = cls + 44000;    // [4000,5]
  float* rois = cls + 64000;    // [4000,5]
  head_kernel<<<1000, 256, 0, stream>>>(H2, wc, bc, wr, br, boxes, cls, bout, rois);
}

// Round 6
// 532.389 us; speedup vs baseline: 1.0942x; 1.0338x over previous
//
#include <hip/hip_runtime.h>
#include <stdint.h>

#define GAS __attribute__((address_space(1)))
#define LAS __attribute__((address_space(3)))

typedef short bf16x8 __attribute__((ext_vector_type(8)));
typedef float f32x4 __attribute__((ext_vector_type(4)));
typedef unsigned short u16x8 __attribute__((ext_vector_type(8)));

__device__ __forceinline__ unsigned short f2bf(float f) {
  union { float f; uint32_t u; } v; v.f = f;
  uint32_t r = v.u + 0x7FFFu + ((v.u >> 16) & 1u);
  return (unsigned short)(r >> 16);
}

// ---------------- fp32 -> bf16 cast, 8 elems/thread ----------------
__global__ __launch_bounds__(256) void cvt_kernel(const float* __restrict__ src,
                                                  unsigned short* __restrict__ dst,
                                                  long n8) {
  long i = (long)blockIdx.x * blockDim.x + threadIdx.x;
  if (i >= n8) return;
  const float4* s4 = (const float4*)src;
  float4 a = s4[i * 2];
  float4 b = s4[i * 2 + 1];
  u16x8 o;
  o[0] = f2bf(a.x); o[1] = f2bf(a.y); o[2] = f2bf(a.z); o[3] = f2bf(a.w);
  o[4] = f2bf(b.x); o[5] = f2bf(b.y); o[6] = f2bf(b.z); o[7] = f2bf(b.w);
  ((u16x8*)dst)[i] = o;
}

// ------------- merged prep: w1/w2 transpose+cast, head-weight transpose -------------
// y < 392: w1 [12544,1024] -> W1T bf16 [1024,12544]
// y < 424: w2 [1024,1024]  -> W2T bf16 [1024,1024]
// y ==424: wc [1024,11], wr [1024,5] -> WhT f32 [16][1024]  (coalesced head reads)
__global__ __launch_bounds__(256) void prep_transpose(const float* __restrict__ w1,
                                                      const float* __restrict__ w2,
                                                      const float* __restrict__ wc,
                                                      const float* __restrict__ wr,
                                                      unsigned short* __restrict__ W1T,
                                                      unsigned short* __restrict__ W2T,
                                                      float* __restrict__ WhT) {
  int tx = threadIdx.x, ty = threadIdx.y;  // 32 x 8
  if ((int)blockIdx.y == 424) {
    int d = blockIdx.x * 32 + tx;  // 0..1023
#pragma unroll
    for (int c = ty; c < 16; c += 8) {
      float v = (c < 11) ? wc[d * 11 + c] : wr[d * 5 + (c - 11)];
      WhT[c * 1024 + d] = v;
    }
    return;
  }
  __shared__ unsigned short tile[32][33];
  const float* src;
  unsigned short* dst;
  int R, yb;
  if ((int)blockIdx.y < 392) {
    src = w1; dst = W1T; R = 12544; yb = blockIdx.y;
  } else {
    src = w2; dst = W2T; R = 1024; yb = blockIdx.y - 392;
  }
  const int C = 1024;
  int r0 = yb * 32, c0 = blockIdx.x * 32;
#pragma unroll
  for (int i = 0; i < 32; i += 8)
    tile[ty + i][tx] = f2bf(src[(long)(r0 + ty + i) * C + c0 + tx]);
  __syncthreads();
#pragma unroll
  for (int i = 0; i < 32; i += 8)
    dst[(long)(c0 + ty + i) * R + r0 + tx] = tile[tx][ty + i];
}

// ---------- GEMM1: 128x128 bf16, XOR-swizzled LDS, split-K x4, atomic (r1-proven) ----------
// A: [M,K] bf16, Bt: [1024,K] bf16 (B transposed). Logical grid 8(xN) x 32(yM) x 4(zK)
// flattened to 1024 with XCD remap: the 8 N-blocks sharing one A-slice land on ONE XCD.
__global__ __launch_bounds__(256, 2) void gemm1_atomic(const unsigned short* __restrict__ A,
                                                       const unsigned short* __restrict__ Bt,
                                                       float* __restrict__ Cv, int M, int K,
                                                       int kIters) {
  __shared__ unsigned short lA[128 * 64];  // 16 KB
  __shared__ unsigned short lB[128 * 64];  // 16 KB
  const int tid = threadIdx.x;
  const int lane = tid & 63;
  const int wave = tid >> 6;
  const int wm = wave >> 1, wn = wave & 1;

  const int b = blockIdx.x;
  const int xcd = b & 7;
  const int slot = b >> 3;
  const int bx = slot & 7;                // N-block, fastest within XCD
  const int pg = xcd * 16 + (slot >> 3);  // (y,z) 0..127
  const int by = pg & 31;
  const int bz = pg >> 5;

  const long rowBase = (long)by * 128;
  const long colBase = (long)bx * 128;
  const int kStart = bz * kIters * 64;

  f32x4 acc[4][4];
#pragma unroll
  for (int i = 0; i < 4; i++)
#pragma unroll
    for (int j = 0; j < 4; j++) acc[i][j] = (f32x4){0.f, 0.f, 0.f, 0.f};

  // flat f = it*256+tid -> LDS slot (r=f>>3, q=f&7) at byte f*16 (wave-uniform+lane*16).
  // XOR swizzle: slot (r,q) holds GLOBAL chunk q^(r&7) -> conflict-free fragment reads.
  long gA[4], gB[4];
#pragma unroll
  for (int it = 0; it < 4; ++it) {
    int f = it * 256 + tid;
    int r = f >> 3;
    int q = f & 7;
    int kq = ((q ^ (r & 7)) * 8) + kStart;
    long ar = rowBase + r;
    if (ar >= M) ar = M - 1;  // clamp: stays in-bounds, C-write masked later
    gA[it] = ar * (long)K + kq;
    gB[it] = ((long)(colBase + r)) * K + kq;
  }

  for (int ki = 0; ki < kIters; ++ki) {
    const long kc = (long)ki * 64;
#pragma unroll
    for (int it = 0; it < 4; ++it) {
      int f = it * 256 + tid;
      __builtin_amdgcn_global_load_lds((const GAS void*)(A + gA[it] + kc),
                                       (LAS void*)(lA + f * 8), 16, 0, 0);
    }
#pragma unroll
    for (int it = 0; it < 4; ++it) {
      int f = it * 256 + tid;
      __builtin_amdgcn_global_load_lds((const GAS void*)(Bt + gB[it] + kc),
                                       (LAS void*)(lB + f * 8), 16, 0, 0);
    }
    __syncthreads();
#pragma unroll
    for (int ks = 0; ks < 64; ks += 32) {
      bf16x8 af[4], bf[4];
      const int c = (ks >> 3) + (lane >> 4);
      const int slotk = (c ^ (lane & 7)) << 3;
      const int mr = wm * 64 + (lane & 15);
      const int nr = wn * 64 + (lane & 15);
#pragma unroll
      for (int i = 0; i < 4; i++)
        af[i] = *(const bf16x8*)(lA + (mr + i * 16) * 64 + slotk);
#pragma unroll
      for (int i = 0; i < 4; i++)
        bf[i] = *(const bf16x8*)(lB + (nr + i * 16) * 64 + slotk);
#pragma unroll
      for (int i = 0; i < 4; i++)
#pragma unroll
        for (int j = 0; j < 4; j++)
          acc[i][j] = __builtin_amdgcn_mfma_f32_16x16x32_bf16(af[i], bf[j], acc[i][j], 0, 0, 0);
    }
    __syncthreads();
  }

  // C/D layout: col=lane&15, row=(lane>>4)*4+reg  [m89-verified]
  const int cq = lane & 15;
  const int rq = (lane >> 4) * 4;
#pragma unroll
  for (int i = 0; i < 4; i++) {
#pragma unroll
    for (int j = 0; j < 4; j++) {
      int col = (int)colBase + wn * 64 + j * 16 + cq;
#pragma unroll
      for (int r = 0; r < 4; r++) {
        long grow = rowBase + wm * 64 + i * 16 + rq + r;
        if (grow < M) unsafeAtomicAdd(&Cv[grow * 1024 + col], acc[i][j][r]);
      }
    }
  }
}

// ---------- GEMM2 fused: A = relu(H1f + b1) computed in-staging (fp32 in, bf16 LDS) ----------
__global__ __launch_bounds__(256, 2) void gemm2_fused(const float* __restrict__ H1f,
                                                      const float* __restrict__ bias1,
                                                      const unsigned short* __restrict__ Bt,
                                                      const float* __restrict__ bias2,
                                                      float* __restrict__ Cv, int M) {
  const int K = 1024;
  __shared__ unsigned short lA[128 * 64];  // 16 KB
  __shared__ unsigned short lB[64 * 64];   // 8 KB
  const int tid = threadIdx.x;
  const int lane = tid & 63;
  const int wave = tid >> 6;
  const int wm = wave >> 1, wn = wave & 1;  // wave tile 64m x 32n

  const int b = blockIdx.x;
  const int xcd = b & 7;
  const int slot = b >> 3;               // 0..63
  const int bx = slot & 15;              // N-block 0..15
  const int by = xcd * 4 + (slot >> 4);  // M-block 0..31

  const long rowBase = (long)by * 128;
  const long colBase = (long)bx * 64;

  f32x4 acc[4][2];
#pragma unroll
  for (int i = 0; i < 4; i++)
#pragma unroll
    for (int j = 0; j < 2; j++) acc[i][j] = (f32x4){0.f, 0.f, 0.f, 0.f};

  long gA[4];
  int aLds[4], aKq[4];
#pragma unroll
  for (int it = 0; it < 4; ++it) {
    int f = it * 256 + tid;
    int r = f >> 3;
    int q = f & 7;
    int kq = (q ^ (r & 7)) * 8;
    long ar = rowBase + r;
    if (ar >= M) ar = M - 1;
    gA[it] = ar * (long)K + kq;
    aLds[it] = f * 8;
    aKq[it] = kq;
  }
  long gB[2];
#pragma unroll
  for (int it = 0; it < 2; ++it) {
    int f = it * 256 + tid;
    int r = f >> 3;
    int q = f & 7;
    int kq = (q ^ (r & 7)) * 8;
    gB[it] = ((long)(colBase + r)) * K + kq;
  }

  for (int ki = 0; ki < 16; ++ki) {
    const long kc = (long)ki * 64;
#pragma unroll
    for (int it = 0; it < 2; ++it) {
      int f = it * 256 + tid;
      __builtin_amdgcn_global_load_lds((const GAS void*)(Bt + gB[it] + kc),
                                       (LAS void*)(lB + f * 8), 16, 0, 0);
    }
    // A: fp32 + bias1 + relu -> bf16 -> LDS
#pragma unroll
    for (int it = 0; it < 4; ++it) {
      const float4* p = (const float4*)(H1f + gA[it] + kc);
      const float4* bp = (const float4*)(bias1 + kc + aKq[it]);
      float4 a = p[0], c = p[1];
      float4 ba = bp[0], bb = bp[1];
      u16x8 v;
      v[0] = f2bf(fmaxf(a.x + ba.x, 0.f)); v[1] = f2bf(fmaxf(a.y + ba.y, 0.f));
      v[2] = f2bf(fmaxf(a.z + ba.z, 0.f)); v[3] = f2bf(fmaxf(a.w + ba.w, 0.f));
      v[4] = f2bf(fmaxf(c.x + bb.x, 0.f)); v[5] = f2bf(fmaxf(c.y + bb.y, 0.f));
      v[6] = f2bf(fmaxf(c.z + bb.z, 0.f)); v[7] = f2bf(fmaxf(c.w + bb.w, 0.f));
      *(u16x8*)(lA + aLds[it]) = v;
    }
    __syncthreads();
#pragma unroll
    for (int ks = 0; ks < 64; ks += 32) {
      bf16x8 af[4], bf[2];
      const int c = (ks >> 3) + (lane >> 4);
      const int slotk = (c ^ (lane & 7)) << 3;
      const int mr = wm * 64 + (lane & 15);
      const int nr = wn * 32 + (lane & 15);
#pragma unroll
      for (int i = 0; i < 4; i++)
        af[i] = *(const bf16x8*)(lA + (mr + i * 16) * 64 + slotk);
#pragma unroll
      for (int j = 0; j < 2; j++)
        bf[j] = *(const bf16x8*)(lB + (nr + j * 16) * 64 + slotk);
#pragma unroll
      for (int i = 0; i < 4; i++)
#pragma unroll
        for (int j = 0; j < 2; j++)
          acc[i][j] = __builtin_amdgcn_mfma_f32_16x16x32_bf16(af[i], bf[j], acc[i][j], 0, 0, 0);
    }
    __syncthreads();
  }

  const int cq = lane & 15;
  const int rq = (lane >> 4) * 4;
#pragma unroll
  for (int i = 0; i < 4; i++) {
#pragma unroll
    for (int j = 0; j < 2; j++) {
      int col = (int)colBase + wn * 32 + j * 16 + cq;
      float bv = bias2[col];
#pragma unroll
      for (int r = 0; r < 4; r++) {
        long grow = rowBase + wm * 64 + i * 16 + rq + r;
        if (grow < M) {
          float v = acc[i][j][r] + bv;
          Cv[grow * 1024 + col] = v > 0.f ? v : 0.f;
        }
      }
    }
  }
}

// ---------------- heads: coalesced via transposed WhT [16][1024] ----------------
__global__ __launch_bounds__(256) void head_t(
    const float* __restrict__ H2, const float* __restrict__ WhT, const float* __restrict__ bc,
    const float* __restrict__ br, const float* __restrict__ boxes,
    float* __restrict__ cls, float* __restrict__ bout, float* __restrict__ rois) {
  const int lane = threadIdx.x & 63;
  const int wave = threadIdx.x >> 6;
  const int row = blockIdx.x * 4 + wave;  // 1000 * 4 = 4000 rows
  const float4* h4 = (const float4*)(H2 + (long)row * 1024);
  float acc[16];
#pragma unroll
  for (int c = 0; c < 16; c++) acc[c] = 0.f;
#pragma unroll
  for (int i = 0; i < 4; i++) {
    float4 hv = h4[i * 64 + lane];
#pragma unroll
    for (int c = 0; c < 16; c++) {
      float4 wv = ((const float4*)(WhT + c * 1024))[i * 64 + lane];
      acc[c] += hv.x * wv.x + hv.y * wv.y + hv.z * wv.z + hv.w * wv.w;
    }
  }
#pragma unroll
  for (int off = 32; off >= 1; off >>= 1) {
#pragma unroll
    for (int c = 0; c < 16; c++) acc[c] += __shfl_down(acc[c], off);
  }
  if (lane == 0) {
#pragma unroll
    for (int c = 0; c < 11; c++) cls[row * 11 + c] = acc[c] + bc[c];
#pragma unroll
    for (int c = 0; c < 5; c++) {
      float rg = acc[11 + c] + br[c];
      float bx = boxes[row * 5 + c];
      bout[row * 5 + c] = bx + rg;
      rois[row * 5 + c] = bx;
    }
  }
}

extern "C" void kernel_launch(void* const* d_in, const int* in_sizes, int n_in,
                              void* d_out, int out_size, void* d_ws, size_t ws_size,
                              hipStream_t stream) {
  const float* features = (const float*)d_in[0];  // [4000,12544] fp32
  const float* boxes = (const float*)d_in[1];
  const float* w1 = (const float*)d_in[2];  // [12544,1024]
  const float* b1 = (const float*)d_in[3];
  const float* w2 = (const float*)d_in[4];  // [1024,1024]
  const float* b2 = (const float*)d_in[5];
  const float* wc = (const float*)d_in[6];  // [1024,11]
  const float* bc = (const float*)d_in[7];
  const float* wr = (const float*)d_in[8];  // [1024,5]
  const float* br = (const float*)d_in[9];

  char* ws = (char*)d_ws;
  unsigned short* Xb  = (unsigned short*)ws;                // 100,352,000 B
  unsigned short* W1T = (unsigned short*)(ws + 100352000);  //  25,690,112 B
  unsigned short* W2T = (unsigned short*)(ws + 126042112);  //   2,097,152 B
  float*          WhT = (float*)(ws + 128139264);           //      65,536 B
  float*          H1f = (float*)(ws + 128204800);           //  16,384,000 B
  float*          H2  = (float*)(ws + 144588800);           //  16,384,000 B
  // total ws used: 160,972,800 B

  // 0) zero split-K accumulator
  hipMemsetAsync(H1f, 0, 16384000, stream);
  // 1) features -> bf16
  cvt_kernel<<<24500, 256, 0, stream>>>(features, Xb, 6272000);
  // 2) prep: w1/w2 transpose+cast, head-weight transpose
  prep_transpose<<<dim3(32, 425), dim3(32, 8), 0, stream>>>(w1, w2, wc, wr, W1T, W2T, WhT);
  // 3) GEMM1 split-K x4 atomic: H1f += Xb @ w1
  gemm1_atomic<<<1024, 256, 0, stream>>>(Xb, W1T, H1f, 4000, 12544, 49);
  // 4) GEMM2 fused: H2 = relu( relu(H1f + b1) @ w2 + b2 )
  gemm2_fused<<<512, 256, 0, stream>>>(H1f, b1, W2T, b2, H2, 4000);
  // 5) heads (coalesced weights)
  float* cls = (float*)d_out;   // [4000,11]
  float* bout = cls + 44000;    // [4000,5]
  float* rois = cls + 64000;    // [4000,5]
  head_t<<<1000, 256, 0, stream>>>(H2, WhT, bc, br, boxes, cls, bout, rois);
}